// Round 8
// baseline (484.225 us; speedup 1.0000x reference)
//
#include <hip/hip_runtime.h>
#include <math.h>

// ---------------------------------------------------------------------------
// Fused 11-layer funnel MLP, round 10.
// Round-9 post-mortem: bA[8]/bB[6] activation arrays passed BY POINTER into
// layer() were never SROA-promoted -> 100% of frag traffic went to scratch
// (FETCH 658MB = exact activation read bytes; VGPR stuck at 64). launch_bounds
// tweaks irrelevant: the allocas were demoted, not spilled.
// Round 10: identical (verified, absmax 0.0) dataflow, but every activation
// fragment is a NAMED u32x4 SSA value; per-tile helper takes inputs by value
// (variadic pack) and returns {lo,hi} by value. No local address is ever
// taken. launch_bounds(1024,1): 16-wave block itself caps regs at 128.
// Structure (from r8):
//  - v_mfma_f32_32x32x16_bf16, 32 rows/wave, weights LDS-resident (90KB),
//    ONE barrier total, 90 weight b128 reads / 0 act DS ops per chunk.
//  - C/D -> next-B relayout: 8x v_cvt_pk_bf16_f32 + 4x v_permlane32_swap
//    per 32-chan tile (pure VALU).
//  - Bias via hi/lo pad cols fed by 1.0-generator rows; tail NP=32.
// ---------------------------------------------------------------------------

using bf16x8 = __attribute__((ext_vector_type(8))) short;   // 8 bf16 = 4 VGPRs
using f32x16 = __attribute__((ext_vector_type(16))) float;
using u32x2v = __attribute__((ext_vector_type(2))) unsigned;
using u32x4  = __attribute__((ext_vector_type(4))) unsigned;
typedef __bf16 bf16x2_t __attribute__((ext_vector_type(2)));

namespace {
constexpr int NL = 11;
constexpr int IN_[NL]   = {15, 30, 60, 90, 120, 90, 60, 30, 15, 10, 5};
constexpr int OUT_[NL]  = {30, 60, 90, 120, 90, 60, 30, 15, 10, 5, 1};
constexpr int KP_[NL]   = {32, 32, 64, 96, 128, 96, 64, 32, 32, 32, 32};  // in, pad 16-gran
constexpr int NP_[NL]   = {32, 64, 96, 128, 96, 64, 32, 32, 32, 32, 32};  // out, pad 32-gran
constexpr int WOFF_[NL] = {0, 1024, 3072, 9216, 21504, 33792, 39936,
                           41984, 43008, 44032, 45056};
constexpr int WTOT      = 46080;                     // shorts (90 KB)
constexpr int WAVES     = 16;
constexpr int THREADS   = WAVES * 64;                // 1024
constexpr int ROWS_PER_WAVE  = 32;
constexpr int ROWS_PER_BLOCK = WAVES * ROWS_PER_WAVE; // 512
constexpr int LDS_BYTES = WTOT * 2;                  // 92160
}

// fp32 -> bf16 RNE (scalar, staging only)
__device__ __forceinline__ unsigned short f2bf(float f) {
    unsigned u = __float_as_uint(f);
    u += 0x7fffu + ((u >> 16) & 1u);
    return (unsigned short)(u >> 16);
}

// packed fp32x2 -> bf16x2 (RNE); gfx950 has v_cvt_pk_bf16_f32
__device__ __forceinline__ unsigned pk2(float a, float b) {
#if __has_builtin(__builtin_amdgcn_cvt_pk_bf16_f32)
    return __builtin_bit_cast(unsigned, __builtin_amdgcn_cvt_pk_bf16_f32(a, b));
#else
    bf16x2_t c;
    c[0] = (__bf16)a;
    c[1] = (__bf16)b;
    return __builtin_bit_cast(unsigned, c);
#endif
}

// permlane32_swap: r[0] = [a_lo, b_lo], r[1] = [a_hi, b_hi]  (VALU, no LDS)
__device__ __forceinline__ u32x2v pls32(unsigned a, unsigned b) {
#if __has_builtin(__builtin_amdgcn_permlane32_swap)
    auto t = __builtin_amdgcn_permlane32_swap(a, b, false, false);
    u32x2v r;
    r[0] = t[0];
    r[1] = t[1];
    return r;
#else
    const int l = (int)(threadIdx.x & 63);
    unsigned bl = (unsigned)__shfl((int)b, l & 31, 64);
    unsigned ah = (unsigned)__shfl((int)a, l | 32, 64);
    u32x2v r;
    r[0] = (l < 32) ? a : bl;
    r[1] = (l < 32) ? ah : b;
    return r;
#endif
}

// Stage layer L's weights as 32x32x16 A-frags (frag-major, 512 shorts/frag).
// A[m][k]: lane = (k_local>>3)*32 + m_local, j = k_local&7.
// Bias folded as pad columns: k==IN -> bias_hi, k==IN+1 -> bias_lo.
// Generator rows m==OUT, OUT+1 emit 1.0 (feed next layer's bias columns).
template <int L>
__device__ __forceinline__ void stage_w(const float* __restrict__ W,
                                        const float* __restrict__ B,
                                        short* wlds, int tid) {
    constexpr int KP = KP_[L], NP = NP_[L], INl = IN_[L], OUTl = OUT_[L];
    constexpr int NKT = KP / 16;
    for (int idx = tid; idx < NP * KP; idx += THREADS) {
        const int f    = idx >> 9;
        const int t    = idx & 511;
        const int ln   = t >> 3;
        const int j    = t & 7;
        const int mloc = ln & 31;
        const int kh   = ln >> 5;
        const int mt   = f / NKT;
        const int kt   = f - mt * NKT;
        const int m    = mt * 32 + mloc;
        const int k    = kt * 16 + kh * 8 + j;
        float v = 0.f;
        if (m < OUTl) {
            if (k < INl) v = W[m * INl + k];
            else if (k == INl) v = B[m];                    // bias_hi
            else if (k == INl + 1) {                        // bias_lo
                float hf = __builtin_bit_cast(float, (unsigned)f2bf(B[m]) << 16);
                v = B[m] - hf;
            }
        } else if (m == OUTl || m == OUTl + 1) {
            if (k == INl) v = 1.f;                          // 1.0-generator row
        }
        wlds[WOFF_[L] + idx] = (short)f2bf(v);
    }
}

struct FragPair { u32x4 lo, hi; };

// Accumulate one 32x32 output tile (mt = MT) of layer L over all K-frags.
// Inputs are BY-VALUE u32x4 fragments (no address taken anywhere).
template <int L, int MT, class... B>
__device__ __forceinline__ f32x16 mt_acc(const short* __restrict__ smem,
                                         int lofs, B... b) {
    constexpr int NKT = (int)sizeof...(B);
    const short* wl = smem + WOFF_[L] + MT * NKT * 512 + lofs;
    f32x16 acc;
#pragma unroll
    for (int i = 0; i < 16; ++i) acc[i] = 0.f;
    int kt = 0;
    ((acc = __builtin_amdgcn_mfma_f32_32x32x16_bf16(
          *(const bf16x8*)(wl + 512 * kt++),
          __builtin_bit_cast(bf16x8, b), acc, 0, 0, 0)), ...);
    return acc;
}

// ReLU + pack + permlane relayout: C/D tile -> two next-layer B-frags.
__device__ __forceinline__ FragPair relayout(f32x16 acc) {
    unsigned p0 = pk2(fmaxf(acc[0],  0.f), fmaxf(acc[1],  0.f));
    unsigned p1 = pk2(fmaxf(acc[2],  0.f), fmaxf(acc[3],  0.f));
    unsigned p2 = pk2(fmaxf(acc[4],  0.f), fmaxf(acc[5],  0.f));
    unsigned p3 = pk2(fmaxf(acc[6],  0.f), fmaxf(acc[7],  0.f));
    unsigned p4 = pk2(fmaxf(acc[8],  0.f), fmaxf(acc[9],  0.f));
    unsigned p5 = pk2(fmaxf(acc[10], 0.f), fmaxf(acc[11], 0.f));
    unsigned p6 = pk2(fmaxf(acc[12], 0.f), fmaxf(acc[13], 0.f));
    unsigned p7 = pk2(fmaxf(acc[14], 0.f), fmaxf(acc[15], 0.f));
    u32x2v r02 = pls32(p0, p2);
    u32x2v r13 = pls32(p1, p3);
    u32x2v r46 = pls32(p4, p6);
    u32x2v r57 = pls32(p5, p7);
    FragPair o;
    o.lo = u32x4{r02[0], r13[0], r02[1], r13[1]};
    o.hi = u32x4{r46[0], r57[0], r46[1], r57[1]};
    return o;
}

template <int L, int MT, class... B>
__device__ __forceinline__ FragPair tile(const short* __restrict__ smem,
                                         int lofs, B... b) {
    return relayout(mt_acc<L, MT>(smem, lofs, b...));
}

__device__ __forceinline__ float4 ld4(const float* p) {
    float4 t;
    __builtin_memcpy(&t, p, 16);
    return t;
}

// Fetch this lane's 8 x-values (h0: k0-7, h1: k8-14 [+bias 1.0]).
__device__ __forceinline__ void fetch_x(const float* __restrict__ x, int row,
                                        int h, float4& t0, float4& t1) {
    const float* p = x + (long)row * 15;
    if (h == 0) { t0 = ld4(p);     t1 = ld4(p + 4);  }
    else        { t0 = ld4(p + 8); t1 = ld4(p + 11); }  // x8-11, x11-14
}

// Build L0's B-frag 0 (k0-15) in registers.
__device__ __forceinline__ u32x4 pack_x(float4 t0, float4 t1, int h) {
    u32x4 b;
    if (h == 0) {
        b[0] = pk2(t0.x, t0.y); b[1] = pk2(t0.z, t0.w);
        b[2] = pk2(t1.x, t1.y); b[3] = pk2(t1.z, t1.w);
    } else {
        b[0] = pk2(t0.x, t0.y); b[1] = pk2(t0.z, t0.w);
        b[2] = pk2(t1.y, t1.z); b[3] = pk2(t1.w, 1.f);   // x12,x13 | x14, bias_hi-mult
    }
    return b;
}

extern "C" __global__ void __launch_bounds__(THREADS, 1)
mlp_fused(const float* __restrict__ x,
          const float* __restrict__ W0,  const float* __restrict__ B0,
          const float* __restrict__ W1,  const float* __restrict__ B1,
          const float* __restrict__ W2,  const float* __restrict__ B2,
          const float* __restrict__ W3,  const float* __restrict__ B3,
          const float* __restrict__ W4,  const float* __restrict__ B4,
          const float* __restrict__ W5,  const float* __restrict__ B5,
          const float* __restrict__ W6,  const float* __restrict__ B6,
          const float* __restrict__ W7,  const float* __restrict__ B7,
          const float* __restrict__ W8,  const float* __restrict__ B8,
          const float* __restrict__ W9,  const float* __restrict__ B9,
          const float* __restrict__ W10, const float* __restrict__ B10,
          float* __restrict__ out, int nchunks) {
    extern __shared__ short smem[];
    const int tid = threadIdx.x;

    stage_w<0>(W0, B0, smem, tid);
    stage_w<1>(W1, B1, smem, tid);
    stage_w<2>(W2, B2, smem, tid);
    stage_w<3>(W3, B3, smem, tid);
    stage_w<4>(W4, B4, smem, tid);
    stage_w<5>(W5, B5, smem, tid);
    stage_w<6>(W6, B6, smem, tid);
    stage_w<7>(W7, B7, smem, tid);
    stage_w<8>(W8, B8, smem, tid);
    stage_w<9>(W9, B9, smem, tid);
    stage_w<10>(W10, B10, smem, tid);
    __syncthreads();   // the only barrier in the kernel

    const int wave = tid >> 6;
    const int lane = tid & 63;
    const int n    = lane & 31;       // batch row within wave tile
    const int hh   = lane >> 5;       // k-half
    const int lofs = lane * 8;        // shorts into a 512-short frag

    int chunk = blockIdx.x;
    float4 t0, t1;
    if (chunk < nchunks)
        fetch_x(x, chunk * ROWS_PER_BLOCK + wave * ROWS_PER_WAVE + n, hh, t0, t1);

    for (; chunk < nchunks; chunk += gridDim.x) {
        const int row0 = chunk * ROWS_PER_BLOCK + wave * ROWS_PER_WAVE;

        u32x4 a0 = pack_x(t0, t1, hh);
        // frag 1 (k16-31): k16 = 1.0 (L0 bias_lo multiplier), rest 0.
        u32x4 a1 = u32x4{hh == 0 ? 0x3F80u : 0u, 0u, 0u, 0u};

        // Prefetch next chunk's x while the layer stack runs.
        const int nxt = chunk + gridDim.x;
        if (nxt < nchunks)
            fetch_x(x, nxt * ROWS_PER_BLOCK + wave * ROWS_PER_WAVE + n, hh, t0, t1);

        FragPair r;
        // L0: 15->30  (2 k-frags -> 1 tile -> 2 frags)
        r = tile<0, 0>(smem, lofs, a0, a1);
        u32x4 b0 = r.lo, b1 = r.hi;
        // L1: 30->60  (2 -> 2 tiles -> 4 frags)
        r = tile<1, 0>(smem, lofs, b0, b1);
        u32x4 c0 = r.lo, c1 = r.hi;
        r = tile<1, 1>(smem, lofs, b0, b1);
        u32x4 c2 = r.lo, c3 = r.hi;
        // L2: 60->90  (4 -> 3 tiles -> 6 frags)
        r = tile<2, 0>(smem, lofs, c0, c1, c2, c3);
        u32x4 d0 = r.lo, d1 = r.hi;
        r = tile<2, 1>(smem, lofs, c0, c1, c2, c3);
        u32x4 d2 = r.lo, d3 = r.hi;
        r = tile<2, 2>(smem, lofs, c0, c1, c2, c3);
        u32x4 d4 = r.lo, d5 = r.hi;
        // L3: 90->120 (6 -> 4 tiles -> 8 frags)
        r = tile<3, 0>(smem, lofs, d0, d1, d2, d3, d4, d5);
        u32x4 e0 = r.lo, e1 = r.hi;
        r = tile<3, 1>(smem, lofs, d0, d1, d2, d3, d4, d5);
        u32x4 e2 = r.lo, e3 = r.hi;
        r = tile<3, 2>(smem, lofs, d0, d1, d2, d3, d4, d5);
        u32x4 e4 = r.lo, e5 = r.hi;
        r = tile<3, 3>(smem, lofs, d0, d1, d2, d3, d4, d5);
        u32x4 e6 = r.lo, e7 = r.hi;
        // L4: 120->90 (8 -> 3 tiles -> 6 frags)
        r = tile<4, 0>(smem, lofs, e0, e1, e2, e3, e4, e5, e6, e7);
        u32x4 f0 = r.lo, f1 = r.hi;
        r = tile<4, 1>(smem, lofs, e0, e1, e2, e3, e4, e5, e6, e7);
        u32x4 f2 = r.lo, f3 = r.hi;
        r = tile<4, 2>(smem, lofs, e0, e1, e2, e3, e4, e5, e6, e7);
        u32x4 f4 = r.lo, f5 = r.hi;
        // L5: 90->60  (6 -> 2 tiles -> 4 frags)
        r = tile<5, 0>(smem, lofs, f0, f1, f2, f3, f4, f5);
        u32x4 g0 = r.lo, g1 = r.hi;
        r = tile<5, 1>(smem, lofs, f0, f1, f2, f3, f4, f5);
        u32x4 g2 = r.lo, g3 = r.hi;
        // L6: 60->30  (4 -> 1 tile -> 2 frags)
        r = tile<6, 0>(smem, lofs, g0, g1, g2, g3);
        u32x4 q0 = r.lo, q1 = r.hi;
        // L7: 30->15
        r = tile<7, 0>(smem, lofs, q0, q1);
        u32x4 s0 = r.lo, s1 = r.hi;
        // L8: 15->10
        r = tile<8, 0>(smem, lofs, s0, s1);
        u32x4 u0 = r.lo, u1 = r.hi;
        // L9: 10->5
        r = tile<9, 0>(smem, lofs, u0, u1);
        u32x4 v0 = r.lo, v1 = r.hi;

        // L10: 5->1 (bias via pads) + sigmoid; channel 0 = acc[0], col=lane.
        {
            f32x16 acc = mt_acc<10, 0>(smem, lofs, v0, v1);
            if (lane < 32)
                out[row0 + lane] = 1.f / (1.f + __expf(-acc[0]));
        }
    }
}

extern "C" void kernel_launch(void* const* d_in, const int* in_sizes, int n_in,
                              void* d_out, int out_size, void* d_ws, size_t ws_size,
                              hipStream_t stream) {
    (void)n_in; (void)d_ws; (void)ws_size; (void)out_size;
    const float* x = (const float*)d_in[0];
    const float* W[11];
    const float* B[11];
    for (int i = 0; i < 11; ++i) {
        W[i] = (const float*)d_in[1 + 2 * i];
        B[i] = (const float*)d_in[2 + 2 * i];
    }
    const int nrows   = in_sizes[0] / 15;
    const int nchunks = nrows / ROWS_PER_BLOCK;   // 524288/512 = 1024

    (void)hipFuncSetAttribute((const void*)mlp_fused,
                              hipFuncAttributeMaxDynamicSharedMemorySize, LDS_BYTES);

    mlp_fused<<<dim3(256), dim3(THREADS), LDS_BYTES, stream>>>(
        x,
        W[0], B[0], W[1], B[1], W[2], B[2], W[3], B[3], W[4], B[4],
        W[5], B[5], W[6], B[6], W[7], B[7], W[8], B[8], W[9], B[9],
        W[10], B[10],
        (float*)d_out, nchunks);
}

// Round 9
// 295.547 us; speedup vs baseline: 1.6384x; 1.6384x over previous
//
#include <hip/hip_runtime.h>
#include <math.h>

// ---------------------------------------------------------------------------
// Fused 11-layer funnel MLP, round 11.
// Round-8/9/10 post-mortem: FETCH/WRITE identical TO THE KB across array,
// launch_bounds(,4), and named-SSA variants -> same codegen every time. Not
// SROA. Diagnosis: unified-RF split -- backend reserves the AGPR side for
// f32x16 MFMA accumulators (r5 observed 64V+64A); at the 128-reg/wave budget
// (16 waves = 4 waves/EU) the VGPR side gets 64 and the ~100-reg activation
// chain spills from it. launch_bounds can only cap regs, not raise the split.
// Round 11: buy a 256-reg/wave budget. 8 waves (512 thr) +
// __attribute__((amdgpu_waves_per_eu(2,2))). The LDS pipe is per-CU, so the
// design floor (90 weight b128 reads x 16384 wave-chunks ~= 69k cy/CU ~29us)
// is occupancy-independent: 8 waves keep it fed (8.6k LDS-cy vs 3.5k
// VALU-cy/SIMD per chunk-round).
// Structure (verified absmax 0.0 in r8/r10):
//  - v_mfma_f32_32x32x16_bf16, 32 rows/wave, weights LDS-resident (90KB),
//    ONE barrier total, 90 weight b128 reads / 0 act DS ops per chunk.
//  - C/D -> next-B relayout: 8x v_cvt_pk_bf16_f32 + 4x v_permlane32_swap
//    per 32-chan tile (pure VALU). Named SSA frags only.
//  - Bias via hi/lo pad cols fed by 1.0-generator rows; tail NP=32.
// ---------------------------------------------------------------------------

using bf16x8 = __attribute__((ext_vector_type(8))) short;   // 8 bf16 = 4 VGPRs
using f32x16 = __attribute__((ext_vector_type(16))) float;
using u32x2v = __attribute__((ext_vector_type(2))) unsigned;
using u32x4  = __attribute__((ext_vector_type(4))) unsigned;
typedef __bf16 bf16x2_t __attribute__((ext_vector_type(2)));

namespace {
constexpr int NL = 11;
constexpr int IN_[NL]   = {15, 30, 60, 90, 120, 90, 60, 30, 15, 10, 5};
constexpr int OUT_[NL]  = {30, 60, 90, 120, 90, 60, 30, 15, 10, 5, 1};
constexpr int KP_[NL]   = {32, 32, 64, 96, 128, 96, 64, 32, 32, 32, 32};  // in, pad 16-gran
constexpr int NP_[NL]   = {32, 64, 96, 128, 96, 64, 32, 32, 32, 32, 32};  // out, pad 32-gran
constexpr int WOFF_[NL] = {0, 1024, 3072, 9216, 21504, 33792, 39936,
                           41984, 43008, 44032, 45056};
constexpr int WTOT      = 46080;                     // shorts (90 KB)
constexpr int WAVES     = 8;
constexpr int THREADS   = WAVES * 64;                // 512
constexpr int ROWS_PER_WAVE  = 32;
constexpr int ROWS_PER_BLOCK = WAVES * ROWS_PER_WAVE; // 256
constexpr int LDS_BYTES = WTOT * 2;                  // 92160
}

// fp32 -> bf16 RNE (scalar, staging only)
__device__ __forceinline__ unsigned short f2bf(float f) {
    unsigned u = __float_as_uint(f);
    u += 0x7fffu + ((u >> 16) & 1u);
    return (unsigned short)(u >> 16);
}

// packed fp32x2 -> bf16x2 (RNE); gfx950 has v_cvt_pk_bf16_f32
__device__ __forceinline__ unsigned pk2(float a, float b) {
#if __has_builtin(__builtin_amdgcn_cvt_pk_bf16_f32)
    return __builtin_bit_cast(unsigned, __builtin_amdgcn_cvt_pk_bf16_f32(a, b));
#else
    bf16x2_t c;
    c[0] = (__bf16)a;
    c[1] = (__bf16)b;
    return __builtin_bit_cast(unsigned, c);
#endif
}

// permlane32_swap: r[0] = [a_lo, b_lo], r[1] = [a_hi, b_hi]  (VALU, no LDS)
__device__ __forceinline__ u32x2v pls32(unsigned a, unsigned b) {
#if __has_builtin(__builtin_amdgcn_permlane32_swap)
    auto t = __builtin_amdgcn_permlane32_swap(a, b, false, false);
    u32x2v r;
    r[0] = t[0];
    r[1] = t[1];
    return r;
#else
    const int l = (int)(threadIdx.x & 63);
    unsigned bl = (unsigned)__shfl((int)b, l & 31, 64);
    unsigned ah = (unsigned)__shfl((int)a, l | 32, 64);
    u32x2v r;
    r[0] = (l < 32) ? a : bl;
    r[1] = (l < 32) ? ah : b;
    return r;
#endif
}

// Stage layer L's weights as 32x32x16 A-frags (frag-major, 512 shorts/frag).
// A[m][k]: lane = (k_local>>3)*32 + m_local, j = k_local&7.
// Bias folded as pad columns: k==IN -> bias_hi, k==IN+1 -> bias_lo.
// Generator rows m==OUT, OUT+1 emit 1.0 (feed next layer's bias columns).
template <int L>
__device__ __forceinline__ void stage_w(const float* __restrict__ W,
                                        const float* __restrict__ B,
                                        short* wlds, int tid) {
    constexpr int KP = KP_[L], NP = NP_[L], INl = IN_[L], OUTl = OUT_[L];
    constexpr int NKT = KP / 16;
    for (int idx = tid; idx < NP * KP; idx += THREADS) {
        const int f    = idx >> 9;
        const int t    = idx & 511;
        const int ln   = t >> 3;
        const int j    = t & 7;
        const int mloc = ln & 31;
        const int kh   = ln >> 5;
        const int mt   = f / NKT;
        const int kt   = f - mt * NKT;
        const int m    = mt * 32 + mloc;
        const int k    = kt * 16 + kh * 8 + j;
        float v = 0.f;
        if (m < OUTl) {
            if (k < INl) v = W[m * INl + k];
            else if (k == INl) v = B[m];                    // bias_hi
            else if (k == INl + 1) {                        // bias_lo
                float hf = __builtin_bit_cast(float, (unsigned)f2bf(B[m]) << 16);
                v = B[m] - hf;
            }
        } else if (m == OUTl || m == OUTl + 1) {
            if (k == INl) v = 1.f;                          // 1.0-generator row
        }
        wlds[WOFF_[L] + idx] = (short)f2bf(v);
    }
}

struct FragPair { u32x4 lo, hi; };

// Accumulate one 32x32 output tile (mt = MT) of layer L over all K-frags.
// Inputs are BY-VALUE u32x4 fragments (no address taken anywhere).
template <int L, int MT, class... B>
__device__ __forceinline__ f32x16 mt_acc(const short* __restrict__ smem,
                                         int lofs, B... b) {
    constexpr int NKT = (int)sizeof...(B);
    const short* wl = smem + WOFF_[L] + MT * NKT * 512 + lofs;
    f32x16 acc;
#pragma unroll
    for (int i = 0; i < 16; ++i) acc[i] = 0.f;
    int kt = 0;
    ((acc = __builtin_amdgcn_mfma_f32_32x32x16_bf16(
          *(const bf16x8*)(wl + 512 * kt++),
          __builtin_bit_cast(bf16x8, b), acc, 0, 0, 0)), ...);
    return acc;
}

// ReLU + pack + permlane relayout: C/D tile -> two next-layer B-frags.
__device__ __forceinline__ FragPair relayout(f32x16 acc) {
    unsigned p0 = pk2(fmaxf(acc[0],  0.f), fmaxf(acc[1],  0.f));
    unsigned p1 = pk2(fmaxf(acc[2],  0.f), fmaxf(acc[3],  0.f));
    unsigned p2 = pk2(fmaxf(acc[4],  0.f), fmaxf(acc[5],  0.f));
    unsigned p3 = pk2(fmaxf(acc[6],  0.f), fmaxf(acc[7],  0.f));
    unsigned p4 = pk2(fmaxf(acc[8],  0.f), fmaxf(acc[9],  0.f));
    unsigned p5 = pk2(fmaxf(acc[10], 0.f), fmaxf(acc[11], 0.f));
    unsigned p6 = pk2(fmaxf(acc[12], 0.f), fmaxf(acc[13], 0.f));
    unsigned p7 = pk2(fmaxf(acc[14], 0.f), fmaxf(acc[15], 0.f));
    u32x2v r02 = pls32(p0, p2);
    u32x2v r13 = pls32(p1, p3);
    u32x2v r46 = pls32(p4, p6);
    u32x2v r57 = pls32(p5, p7);
    FragPair o;
    o.lo = u32x4{r02[0], r13[0], r02[1], r13[1]};
    o.hi = u32x4{r46[0], r57[0], r46[1], r57[1]};
    return o;
}

template <int L, int MT, class... B>
__device__ __forceinline__ FragPair tile(const short* __restrict__ smem,
                                         int lofs, B... b) {
    return relayout(mt_acc<L, MT>(smem, lofs, b...));
}

__device__ __forceinline__ float4 ld4(const float* p) {
    float4 t;
    __builtin_memcpy(&t, p, 16);
    return t;
}

// Fetch this lane's 8 x-values (h0: k0-7, h1: k8-14 [+bias 1.0]).
__device__ __forceinline__ void fetch_x(const float* __restrict__ x, int row,
                                        int h, float4& t0, float4& t1) {
    const float* p = x + (long)row * 15;
    if (h == 0) { t0 = ld4(p);     t1 = ld4(p + 4);  }
    else        { t0 = ld4(p + 8); t1 = ld4(p + 11); }  // x8-11, x11-14
}

// Build L0's B-frag 0 (k0-15) in registers.
__device__ __forceinline__ u32x4 pack_x(float4 t0, float4 t1, int h) {
    u32x4 b;
    if (h == 0) {
        b[0] = pk2(t0.x, t0.y); b[1] = pk2(t0.z, t0.w);
        b[2] = pk2(t1.x, t1.y); b[3] = pk2(t1.z, t1.w);
    } else {
        b[0] = pk2(t0.x, t0.y); b[1] = pk2(t0.z, t0.w);
        b[2] = pk2(t1.y, t1.z); b[3] = pk2(t1.w, 1.f);   // x12,x13 | x14, bias_hi-mult
    }
    return b;
}

extern "C" __global__ void __launch_bounds__(THREADS)
__attribute__((amdgpu_waves_per_eu(2, 2)))
mlp_fused(const float* __restrict__ x,
          const float* __restrict__ W0,  const float* __restrict__ B0,
          const float* __restrict__ W1,  const float* __restrict__ B1,
          const float* __restrict__ W2,  const float* __restrict__ B2,
          const float* __restrict__ W3,  const float* __restrict__ B3,
          const float* __restrict__ W4,  const float* __restrict__ B4,
          const float* __restrict__ W5,  const float* __restrict__ B5,
          const float* __restrict__ W6,  const float* __restrict__ B6,
          const float* __restrict__ W7,  const float* __restrict__ B7,
          const float* __restrict__ W8,  const float* __restrict__ B8,
          const float* __restrict__ W9,  const float* __restrict__ B9,
          const float* __restrict__ W10, const float* __restrict__ B10,
          float* __restrict__ out, int nchunks) {
    extern __shared__ short smem[];
    const int tid = threadIdx.x;

    stage_w<0>(W0, B0, smem, tid);
    stage_w<1>(W1, B1, smem, tid);
    stage_w<2>(W2, B2, smem, tid);
    stage_w<3>(W3, B3, smem, tid);
    stage_w<4>(W4, B4, smem, tid);
    stage_w<5>(W5, B5, smem, tid);
    stage_w<6>(W6, B6, smem, tid);
    stage_w<7>(W7, B7, smem, tid);
    stage_w<8>(W8, B8, smem, tid);
    stage_w<9>(W9, B9, smem, tid);
    stage_w<10>(W10, B10, smem, tid);
    __syncthreads();   // the only barrier in the kernel

    const int wave = tid >> 6;
    const int lane = tid & 63;
    const int n    = lane & 31;       // batch row within wave tile
    const int hh   = lane >> 5;       // k-half
    const int lofs = lane * 8;        // shorts into a 512-short frag

    int chunk = blockIdx.x;
    float4 t0, t1;
    if (chunk < nchunks)
        fetch_x(x, chunk * ROWS_PER_BLOCK + wave * ROWS_PER_WAVE + n, hh, t0, t1);

    for (; chunk < nchunks; chunk += gridDim.x) {
        const int row0 = chunk * ROWS_PER_BLOCK + wave * ROWS_PER_WAVE;

        u32x4 a0 = pack_x(t0, t1, hh);
        // frag 1 (k16-31): k16 = 1.0 (L0 bias_lo multiplier), rest 0.
        u32x4 a1 = u32x4{hh == 0 ? 0x3F80u : 0u, 0u, 0u, 0u};

        // Prefetch next chunk's x while the layer stack runs.
        const int nxt = chunk + gridDim.x;
        if (nxt < nchunks)
            fetch_x(x, nxt * ROWS_PER_BLOCK + wave * ROWS_PER_WAVE + n, hh, t0, t1);

        FragPair r;
        // L0: 15->30  (2 k-frags -> 1 tile -> 2 frags)
        r = tile<0, 0>(smem, lofs, a0, a1);
        u32x4 b0 = r.lo, b1 = r.hi;
        // L1: 30->60  (2 -> 2 tiles -> 4 frags)
        r = tile<1, 0>(smem, lofs, b0, b1);
        u32x4 c0 = r.lo, c1 = r.hi;
        r = tile<1, 1>(smem, lofs, b0, b1);
        u32x4 c2 = r.lo, c3 = r.hi;
        // L2: 60->90  (4 -> 3 tiles -> 6 frags)
        r = tile<2, 0>(smem, lofs, c0, c1, c2, c3);
        u32x4 d0 = r.lo, d1 = r.hi;
        r = tile<2, 1>(smem, lofs, c0, c1, c2, c3);
        u32x4 d2 = r.lo, d3 = r.hi;
        r = tile<2, 2>(smem, lofs, c0, c1, c2, c3);
        u32x4 d4 = r.lo, d5 = r.hi;
        // L3: 90->120 (6 -> 4 tiles -> 8 frags)
        r = tile<3, 0>(smem, lofs, d0, d1, d2, d3, d4, d5);
        u32x4 e0 = r.lo, e1 = r.hi;
        r = tile<3, 1>(smem, lofs, d0, d1, d2, d3, d4, d5);
        u32x4 e2 = r.lo, e3 = r.hi;
        r = tile<3, 2>(smem, lofs, d0, d1, d2, d3, d4, d5);
        u32x4 e4 = r.lo, e5 = r.hi;
        r = tile<3, 3>(smem, lofs, d0, d1, d2, d3, d4, d5);
        u32x4 e6 = r.lo, e7 = r.hi;
        // L4: 120->90 (8 -> 3 tiles -> 6 frags)
        r = tile<4, 0>(smem, lofs, e0, e1, e2, e3, e4, e5, e6, e7);
        u32x4 f0 = r.lo, f1 = r.hi;
        r = tile<4, 1>(smem, lofs, e0, e1, e2, e3, e4, e5, e6, e7);
        u32x4 f2 = r.lo, f3 = r.hi;
        r = tile<4, 2>(smem, lofs, e0, e1, e2, e3, e4, e5, e6, e7);
        u32x4 f4 = r.lo, f5 = r.hi;
        // L5: 90->60  (6 -> 2 tiles -> 4 frags)
        r = tile<5, 0>(smem, lofs, f0, f1, f2, f3, f4, f5);
        u32x4 g0 = r.lo, g1 = r.hi;
        r = tile<5, 1>(smem, lofs, f0, f1, f2, f3, f4, f5);
        u32x4 g2 = r.lo, g3 = r.hi;
        // L6: 60->30  (4 -> 1 tile -> 2 frags)
        r = tile<6, 0>(smem, lofs, g0, g1, g2, g3);
        u32x4 q0 = r.lo, q1 = r.hi;
        // L7: 30->15
        r = tile<7, 0>(smem, lofs, q0, q1);
        u32x4 s0 = r.lo, s1 = r.hi;
        // L8: 15->10
        r = tile<8, 0>(smem, lofs, s0, s1);
        u32x4 u0 = r.lo, u1 = r.hi;
        // L9: 10->5
        r = tile<9, 0>(smem, lofs, u0, u1);
        u32x4 v0 = r.lo, v1 = r.hi;

        // L10: 5->1 (bias via pads) + sigmoid; channel 0 = acc[0], col=lane.
        {
            f32x16 acc = mt_acc<10, 0>(smem, lofs, v0, v1);
            if (lane < 32)
                out[row0 + lane] = 1.f / (1.f + __expf(-acc[0]));
        }
    }
}

extern "C" void kernel_launch(void* const* d_in, const int* in_sizes, int n_in,
                              void* d_out, int out_size, void* d_ws, size_t ws_size,
                              hipStream_t stream) {
    (void)n_in; (void)d_ws; (void)ws_size; (void)out_size;
    const float* x = (const float*)d_in[0];
    const float* W[11];
    const float* B[11];
    for (int i = 0; i < 11; ++i) {
        W[i] = (const float*)d_in[1 + 2 * i];
        B[i] = (const float*)d_in[2 + 2 * i];
    }
    const int nrows   = in_sizes[0] / 15;
    const int nchunks = nrows / ROWS_PER_BLOCK;   // 524288/256 = 2048

    (void)hipFuncSetAttribute((const void*)mlp_fused,
                              hipFuncAttributeMaxDynamicSharedMemorySize, LDS_BYTES);

    mlp_fused<<<dim3(256), dim3(THREADS), LDS_BYTES, stream>>>(
        x,
        W[0], B[0], W[1], B[1], W[2], B[2], W[3], B[3], W[4], B[4],
        W[5], B[5], W[6], B[6], W[7], B[7], W[8], B[8], W[9], B[9],
        W[10], B[10],
        (float*)d_out, nchunks);
}

// Round 10
// 230.832 us; speedup vs baseline: 2.0977x; 1.2804x over previous
//
#include <hip/hip_runtime.h>
#include <math.h>

// ---------------------------------------------------------------------------
// Fused 11-layer funnel MLP, round 12.
// Round-11 post-mortem: reg-budget theory CONFIRMED by gradient -- arch VGPR
// 64->128 halved scratch (658->394MB FETCH, 380->198us). At a 256-reg cap the
// unified RF splits 128V+128A and the ~110-reg chain still spills from the V
// side. Round 12: occupancy-1. 256-thread blocks (4 waves) +
// amdgpu_waves_per_eu(1,1) -> 512-reg/wave budget -> ~256 arch VGPRs.
// TLP loss is affordable: the LDS weight-read floor is per-CU (~69k cy =
// ~29us) and each wave's per-chunk critical path (~2-3k cy x 16 chunks =
// ~17us) sits below it, so the LDS pipe stays the binding resource.
// Structure (verified absmax 0.0 in r8/r10/r11):
//  - v_mfma_f32_32x32x16_bf16, 32 rows/wave, weights LDS-resident (90KB),
//    ONE barrier total, 90 weight b128 reads / 0 act DS ops per chunk.
//  - C/D -> next-B relayout: 8x v_cvt_pk_bf16_f32 + 4x v_permlane32_swap
//    per 32-chan tile (pure VALU). Named SSA frags only.
//  - Bias via hi/lo pad cols fed by 1.0-generator rows; tail NP=32.
// ---------------------------------------------------------------------------

using bf16x8 = __attribute__((ext_vector_type(8))) short;   // 8 bf16 = 4 VGPRs
using f32x16 = __attribute__((ext_vector_type(16))) float;
using u32x2v = __attribute__((ext_vector_type(2))) unsigned;
using u32x4  = __attribute__((ext_vector_type(4))) unsigned;
typedef __bf16 bf16x2_t __attribute__((ext_vector_type(2)));

namespace {
constexpr int NL = 11;
constexpr int IN_[NL]   = {15, 30, 60, 90, 120, 90, 60, 30, 15, 10, 5};
constexpr int OUT_[NL]  = {30, 60, 90, 120, 90, 60, 30, 15, 10, 5, 1};
constexpr int KP_[NL]   = {32, 32, 64, 96, 128, 96, 64, 32, 32, 32, 32};  // in, pad 16-gran
constexpr int NP_[NL]   = {32, 64, 96, 128, 96, 64, 32, 32, 32, 32, 32};  // out, pad 32-gran
constexpr int WOFF_[NL] = {0, 1024, 3072, 9216, 21504, 33792, 39936,
                           41984, 43008, 44032, 45056};
constexpr int WTOT      = 46080;                     // shorts (90 KB)
constexpr int WAVES     = 4;
constexpr int THREADS   = WAVES * 64;                // 256
constexpr int ROWS_PER_WAVE  = 32;
constexpr int ROWS_PER_BLOCK = WAVES * ROWS_PER_WAVE; // 128
constexpr int LDS_BYTES = WTOT * 2;                  // 92160
}

// fp32 -> bf16 RNE (scalar, staging only)
__device__ __forceinline__ unsigned short f2bf(float f) {
    unsigned u = __float_as_uint(f);
    u += 0x7fffu + ((u >> 16) & 1u);
    return (unsigned short)(u >> 16);
}

// packed fp32x2 -> bf16x2 (RNE); gfx950 has v_cvt_pk_bf16_f32
__device__ __forceinline__ unsigned pk2(float a, float b) {
#if __has_builtin(__builtin_amdgcn_cvt_pk_bf16_f32)
    return __builtin_bit_cast(unsigned, __builtin_amdgcn_cvt_pk_bf16_f32(a, b));
#else
    bf16x2_t c;
    c[0] = (__bf16)a;
    c[1] = (__bf16)b;
    return __builtin_bit_cast(unsigned, c);
#endif
}

// permlane32_swap: r[0] = [a_lo, b_lo], r[1] = [a_hi, b_hi]  (VALU, no LDS)
__device__ __forceinline__ u32x2v pls32(unsigned a, unsigned b) {
#if __has_builtin(__builtin_amdgcn_permlane32_swap)
    auto t = __builtin_amdgcn_permlane32_swap(a, b, false, false);
    u32x2v r;
    r[0] = t[0];
    r[1] = t[1];
    return r;
#else
    const int l = (int)(threadIdx.x & 63);
    unsigned bl = (unsigned)__shfl((int)b, l & 31, 64);
    unsigned ah = (unsigned)__shfl((int)a, l | 32, 64);
    u32x2v r;
    r[0] = (l < 32) ? a : bl;
    r[1] = (l < 32) ? ah : b;
    return r;
#endif
}

// Stage layer L's weights as 32x32x16 A-frags (frag-major, 512 shorts/frag).
// A[m][k]: lane = (k_local>>3)*32 + m_local, j = k_local&7.
// Bias folded as pad columns: k==IN -> bias_hi, k==IN+1 -> bias_lo.
// Generator rows m==OUT, OUT+1 emit 1.0 (feed next layer's bias columns).
template <int L>
__device__ __forceinline__ void stage_w(const float* __restrict__ W,
                                        const float* __restrict__ B,
                                        short* wlds, int tid) {
    constexpr int KP = KP_[L], NP = NP_[L], INl = IN_[L], OUTl = OUT_[L];
    constexpr int NKT = KP / 16;
    for (int idx = tid; idx < NP * KP; idx += THREADS) {
        const int f    = idx >> 9;
        const int t    = idx & 511;
        const int ln   = t >> 3;
        const int j    = t & 7;
        const int mloc = ln & 31;
        const int kh   = ln >> 5;
        const int mt   = f / NKT;
        const int kt   = f - mt * NKT;
        const int m    = mt * 32 + mloc;
        const int k    = kt * 16 + kh * 8 + j;
        float v = 0.f;
        if (m < OUTl) {
            if (k < INl) v = W[m * INl + k];
            else if (k == INl) v = B[m];                    // bias_hi
            else if (k == INl + 1) {                        // bias_lo
                float hf = __builtin_bit_cast(float, (unsigned)f2bf(B[m]) << 16);
                v = B[m] - hf;
            }
        } else if (m == OUTl || m == OUTl + 1) {
            if (k == INl) v = 1.f;                          // 1.0-generator row
        }
        wlds[WOFF_[L] + idx] = (short)f2bf(v);
    }
}

struct FragPair { u32x4 lo, hi; };

// Accumulate one 32x32 output tile (mt = MT) of layer L over all K-frags.
// Inputs are BY-VALUE u32x4 fragments (no address taken anywhere).
template <int L, int MT, class... B>
__device__ __forceinline__ f32x16 mt_acc(const short* __restrict__ smem,
                                         int lofs, B... b) {
    constexpr int NKT = (int)sizeof...(B);
    const short* wl = smem + WOFF_[L] + MT * NKT * 512 + lofs;
    f32x16 acc;
#pragma unroll
    for (int i = 0; i < 16; ++i) acc[i] = 0.f;
    int kt = 0;
    ((acc = __builtin_amdgcn_mfma_f32_32x32x16_bf16(
          *(const bf16x8*)(wl + 512 * kt++),
          __builtin_bit_cast(bf16x8, b), acc, 0, 0, 0)), ...);
    return acc;
}

// ReLU + pack + permlane relayout: C/D tile -> two next-layer B-frags.
__device__ __forceinline__ FragPair relayout(f32x16 acc) {
    unsigned p0 = pk2(fmaxf(acc[0],  0.f), fmaxf(acc[1],  0.f));
    unsigned p1 = pk2(fmaxf(acc[2],  0.f), fmaxf(acc[3],  0.f));
    unsigned p2 = pk2(fmaxf(acc[4],  0.f), fmaxf(acc[5],  0.f));
    unsigned p3 = pk2(fmaxf(acc[6],  0.f), fmaxf(acc[7],  0.f));
    unsigned p4 = pk2(fmaxf(acc[8],  0.f), fmaxf(acc[9],  0.f));
    unsigned p5 = pk2(fmaxf(acc[10], 0.f), fmaxf(acc[11], 0.f));
    unsigned p6 = pk2(fmaxf(acc[12], 0.f), fmaxf(acc[13], 0.f));
    unsigned p7 = pk2(fmaxf(acc[14], 0.f), fmaxf(acc[15], 0.f));
    u32x2v r02 = pls32(p0, p2);
    u32x2v r13 = pls32(p1, p3);
    u32x2v r46 = pls32(p4, p6);
    u32x2v r57 = pls32(p5, p7);
    FragPair o;
    o.lo = u32x4{r02[0], r13[0], r02[1], r13[1]};
    o.hi = u32x4{r46[0], r57[0], r46[1], r57[1]};
    return o;
}

template <int L, int MT, class... B>
__device__ __forceinline__ FragPair tile(const short* __restrict__ smem,
                                         int lofs, B... b) {
    return relayout(mt_acc<L, MT>(smem, lofs, b...));
}

__device__ __forceinline__ float4 ld4(const float* p) {
    float4 t;
    __builtin_memcpy(&t, p, 16);
    return t;
}

// Fetch this lane's 8 x-values (h0: k0-7, h1: k8-14 [+bias 1.0]).
__device__ __forceinline__ void fetch_x(const float* __restrict__ x, int row,
                                        int h, float4& t0, float4& t1) {
    const float* p = x + (long)row * 15;
    if (h == 0) { t0 = ld4(p);     t1 = ld4(p + 4);  }
    else        { t0 = ld4(p + 8); t1 = ld4(p + 11); }  // x8-11, x11-14
}

// Build L0's B-frag 0 (k0-15) in registers.
__device__ __forceinline__ u32x4 pack_x(float4 t0, float4 t1, int h) {
    u32x4 b;
    if (h == 0) {
        b[0] = pk2(t0.x, t0.y); b[1] = pk2(t0.z, t0.w);
        b[2] = pk2(t1.x, t1.y); b[3] = pk2(t1.z, t1.w);
    } else {
        b[0] = pk2(t0.x, t0.y); b[1] = pk2(t0.z, t0.w);
        b[2] = pk2(t1.y, t1.z); b[3] = pk2(t1.w, 1.f);   // x12,x13 | x14, bias_hi-mult
    }
    return b;
}

extern "C" __global__ void __launch_bounds__(THREADS)
__attribute__((amdgpu_waves_per_eu(1, 1)))
mlp_fused(const float* __restrict__ x,
          const float* __restrict__ W0,  const float* __restrict__ B0,
          const float* __restrict__ W1,  const float* __restrict__ B1,
          const float* __restrict__ W2,  const float* __restrict__ B2,
          const float* __restrict__ W3,  const float* __restrict__ B3,
          const float* __restrict__ W4,  const float* __restrict__ B4,
          const float* __restrict__ W5,  const float* __restrict__ B5,
          const float* __restrict__ W6,  const float* __restrict__ B6,
          const float* __restrict__ W7,  const float* __restrict__ B7,
          const float* __restrict__ W8,  const float* __restrict__ B8,
          const float* __restrict__ W9,  const float* __restrict__ B9,
          const float* __restrict__ W10, const float* __restrict__ B10,
          float* __restrict__ out, int nchunks) {
    extern __shared__ short smem[];
    const int tid = threadIdx.x;

    stage_w<0>(W0, B0, smem, tid);
    stage_w<1>(W1, B1, smem, tid);
    stage_w<2>(W2, B2, smem, tid);
    stage_w<3>(W3, B3, smem, tid);
    stage_w<4>(W4, B4, smem, tid);
    stage_w<5>(W5, B5, smem, tid);
    stage_w<6>(W6, B6, smem, tid);
    stage_w<7>(W7, B7, smem, tid);
    stage_w<8>(W8, B8, smem, tid);
    stage_w<9>(W9, B9, smem, tid);
    stage_w<10>(W10, B10, smem, tid);
    __syncthreads();   // the only barrier in the kernel

    const int wave = tid >> 6;
    const int lane = tid & 63;
    const int n    = lane & 31;       // batch row within wave tile
    const int hh   = lane >> 5;       // k-half
    const int lofs = lane * 8;        // shorts into a 512-short frag

    int chunk = blockIdx.x;
    float4 t0, t1;
    if (chunk < nchunks)
        fetch_x(x, chunk * ROWS_PER_BLOCK + wave * ROWS_PER_WAVE + n, hh, t0, t1);

    for (; chunk < nchunks; chunk += gridDim.x) {
        const int row0 = chunk * ROWS_PER_BLOCK + wave * ROWS_PER_WAVE;

        u32x4 a0 = pack_x(t0, t1, hh);
        // frag 1 (k16-31): k16 = 1.0 (L0 bias_lo multiplier), rest 0.
        u32x4 a1 = u32x4{hh == 0 ? 0x3F80u : 0u, 0u, 0u, 0u};

        // Prefetch next chunk's x while the layer stack runs.
        const int nxt = chunk + gridDim.x;
        if (nxt < nchunks)
            fetch_x(x, nxt * ROWS_PER_BLOCK + wave * ROWS_PER_WAVE + n, hh, t0, t1);

        FragPair r;
        // L0: 15->30  (2 k-frags -> 1 tile -> 2 frags)
        r = tile<0, 0>(smem, lofs, a0, a1);
        u32x4 b0 = r.lo, b1 = r.hi;
        // L1: 30->60  (2 -> 2 tiles -> 4 frags)
        r = tile<1, 0>(smem, lofs, b0, b1);
        u32x4 c0 = r.lo, c1 = r.hi;
        r = tile<1, 1>(smem, lofs, b0, b1);
        u32x4 c2 = r.lo, c3 = r.hi;
        // L2: 60->90  (4 -> 3 tiles -> 6 frags)
        r = tile<2, 0>(smem, lofs, c0, c1, c2, c3);
        u32x4 d0 = r.lo, d1 = r.hi;
        r = tile<2, 1>(smem, lofs, c0, c1, c2, c3);
        u32x4 d2 = r.lo, d3 = r.hi;
        r = tile<2, 2>(smem, lofs, c0, c1, c2, c3);
        u32x4 d4 = r.lo, d5 = r.hi;
        // L3: 90->120 (6 -> 4 tiles -> 8 frags)
        r = tile<3, 0>(smem, lofs, d0, d1, d2, d3, d4, d5);
        u32x4 e0 = r.lo, e1 = r.hi;
        r = tile<3, 1>(smem, lofs, d0, d1, d2, d3, d4, d5);
        u32x4 e2 = r.lo, e3 = r.hi;
        r = tile<3, 2>(smem, lofs, d0, d1, d2, d3, d4, d5);
        u32x4 e4 = r.lo, e5 = r.hi;
        r = tile<3, 3>(smem, lofs, d0, d1, d2, d3, d4, d5);
        u32x4 e6 = r.lo, e7 = r.hi;
        // L4: 120->90 (8 -> 3 tiles -> 6 frags)
        r = tile<4, 0>(smem, lofs, e0, e1, e2, e3, e4, e5, e6, e7);
        u32x4 f0 = r.lo, f1 = r.hi;
        r = tile<4, 1>(smem, lofs, e0, e1, e2, e3, e4, e5, e6, e7);
        u32x4 f2 = r.lo, f3 = r.hi;
        r = tile<4, 2>(smem, lofs, e0, e1, e2, e3, e4, e5, e6, e7);
        u32x4 f4 = r.lo, f5 = r.hi;
        // L5: 90->60  (6 -> 2 tiles -> 4 frags)
        r = tile<5, 0>(smem, lofs, f0, f1, f2, f3, f4, f5);
        u32x4 g0 = r.lo, g1 = r.hi;
        r = tile<5, 1>(smem, lofs, f0, f1, f2, f3, f4, f5);
        u32x4 g2 = r.lo, g3 = r.hi;
        // L6: 60->30  (4 -> 1 tile -> 2 frags)
        r = tile<6, 0>(smem, lofs, g0, g1, g2, g3);
        u32x4 q0 = r.lo, q1 = r.hi;
        // L7: 30->15
        r = tile<7, 0>(smem, lofs, q0, q1);
        u32x4 s0 = r.lo, s1 = r.hi;
        // L8: 15->10
        r = tile<8, 0>(smem, lofs, s0, s1);
        u32x4 u0 = r.lo, u1 = r.hi;
        // L9: 10->5
        r = tile<9, 0>(smem, lofs, u0, u1);
        u32x4 v0 = r.lo, v1 = r.hi;

        // L10: 5->1 (bias via pads) + sigmoid; channel 0 = acc[0], col=lane.
        {
            f32x16 acc = mt_acc<10, 0>(smem, lofs, v0, v1);
            if (lane < 32)
                out[row0 + lane] = 1.f / (1.f + __expf(-acc[0]));
        }
    }
}

extern "C" void kernel_launch(void* const* d_in, const int* in_sizes, int n_in,
                              void* d_out, int out_size, void* d_ws, size_t ws_size,
                              hipStream_t stream) {
    (void)n_in; (void)d_ws; (void)ws_size; (void)out_size;
    const float* x = (const float*)d_in[0];
    const float* W[11];
    const float* B[11];
    for (int i = 0; i < 11; ++i) {
        W[i] = (const float*)d_in[1 + 2 * i];
        B[i] = (const float*)d_in[2 + 2 * i];
    }
    const int nrows   = in_sizes[0] / 15;
    const int nchunks = nrows / ROWS_PER_BLOCK;   // 524288/128 = 4096

    (void)hipFuncSetAttribute((const void*)mlp_fused,
                              hipFuncAttributeMaxDynamicSharedMemorySize, LDS_BYTES);

    mlp_fused<<<dim3(256), dim3(THREADS), LDS_BYTES, stream>>>(
        x,
        W[0], B[0], W[1], B[1], W[2], B[2], W[3], B[3], W[4], B[4],
        W[5], B[5], W[6], B[6], W[7], B[7], W[8], B[8], W[9], B[9],
        W[10], B[10],
        (float*)d_out, nchunks);
}